// Round 7
// baseline (110.093 us; speedup 1.0000x reference)
//
#include <hip/hip_runtime.h>

#define K   16          // tracked labels 1..16 (label 0 = background, never in loss)
#define NB  16          // batch
#define NP  409600      // 640*640 pixels per image
#define NPV (NP / 4)    // float4 vectors per image
#define BX  128         // blocks per image -> 2048 blocks = 8 blocks/CU = 32 waves/CU
#define NBLK (NB * BX)
#define SIGMA_DIS 3.0f

// ---------------- Stage 1: per-(b,label) sum of squared norms + counts ----------------
// Lane-privatized LDS histogram, one set per PAIR of waves (19.5 KB -> 8 blocks/CU).
// Updates are non-returning LDS atomicAdd (ds_add_f32): fire-and-forget, no
// read-modify-write dependency chain; inter-wave same-slot collisions (~1/17)
// are absorbed by the LDS atomic unit.
__global__ __launch_bounds__(256) void seg_reduce_kernel(
    const float* __restrict__ pred,   // (NB, 4, NP)
    const int*   __restrict__ lab,    // (NB, NP)
    float* __restrict__ ss_part,      // (K, NBLK)  transposed for coalesced stage-2 reads
    float* __restrict__ cnt_part)     // (K, NBLK)
{
    __shared__ float ss_h [2][17 * 64];   // 8704 B
    __shared__ float cnt_h[2][17 * 64];   // 8704 B
    __shared__ float2 red[16][16];        // 2048 B   -> 19456 B total: 8 blocks/CU

    const int tid  = threadIdx.x;
    const int lane = tid & 63;
    const int set  = tid >> 7;            // waves {0,1} -> set 0, waves {2,3} -> set 1
    const int b    = blockIdx.y;
    const int bx   = blockIdx.x;
    const int blk  = b * BX + bx;

    for (int e = tid; e < 2 * 17 * 64; e += 256) {
        (&ss_h [0][0])[e] = 0.0f;
        (&cnt_h[0][0])[e] = 0.0f;
    }
    __syncthreads();

    float* ssl  = &ss_h [set][lane];      // label k lives at ssl[k * 64]
    float* cntl = &cnt_h[set][lane];

    const float4* p0 = (const float4*)(pred + ((size_t)b * 4 + 0) * NP);
    const float4* p1 = (const float4*)(pred + ((size_t)b * 4 + 1) * NP);
    const float4* p2 = (const float4*)(pred + ((size_t)b * 4 + 2) * NP);
    const float4* p3 = (const float4*)(pred + ((size_t)b * 4 + 3) * NP);
    const int4*   lb = (const int4*)(lab + (size_t)b * NP);

    // bx*256, stride and NPV are multiples of 256 -> guard is block-uniform.
    for (int v = bx * 256 + tid; v < NPV; v += BX * 256) {
        float4 a = p0[v];
        float4 c = p1[v];
        float4 d = p2[v];
        float4 e = p3[v];
        int4   l = lb[v];

        float s0 = a.x * a.x + c.x * c.x + d.x * d.x + e.x * e.x;
        float s1 = a.y * a.y + c.y * c.y + d.y * d.y + e.y * e.y;
        float s2 = a.z * a.z + c.z * c.z + d.z * d.z + e.z * e.z;
        float s3 = a.w * a.w + c.w * c.w + d.w * d.w + e.w * e.w;

        atomicAdd(&ssl [l.x * 64], s0);  atomicAdd(&cntl[l.x * 64], 1.0f);
        atomicAdd(&ssl [l.y * 64], s1);  atomicAdd(&cntl[l.y * 64], 1.0f);
        atomicAdd(&ssl [l.z * 64], s2);  atomicAdd(&cntl[l.z * 64], 1.0f);
        atomicAdd(&ssl [l.w * 64], s3);  atomicAdd(&cntl[l.w * 64], 1.0f);
    }
    __syncthreads();

    // --- block reduce: 128 slots (set, lane) per label; 16 threads per label, 8 slots each ---
    {
        const int rk = (tid & 15) + 1;    // label 1..16 (bin 0 = background, dropped)
        const int rs = tid >> 4;          // slot group 0..15
        float ssa = 0.0f, cca = 0.0f;
#pragma unroll
        for (int j = 0; j < 8; ++j) {
            const int slot = rs * 8 + j;              // 0..127
            ssa += ss_h [slot >> 6][rk * 64 + (slot & 63)];
            cca += cnt_h[slot >> 6][rk * 64 + (slot & 63)];
        }
        red[tid & 15][rs] = make_float2(ssa, cca);
    }
    __syncthreads();

    if (tid < 16) {
        float ss = 0.0f, cc = 0.0f;
#pragma unroll
        for (int s = 0; s < 16; ++s) { ss += red[tid][s].x; cc += red[tid][s].y; }
        ss_part [tid * NBLK + blk] = ss;
        cnt_part[tid * NBLK + blk] = cc;
    }
}

// ---------------- Stage 2: combine partials + pairwise loss ----------------
__global__ __launch_bounds__(256) void finalize_kernel(
    const float* __restrict__ ss_part,
    const float* __restrict__ cnt_part,
    float* __restrict__ out)
{
    __shared__ float m_sh[NB][K];
    __shared__ float c_sh[NB][K];
    __shared__ float inv_denom[NB];
    __shared__ float red[256];

    const int t = threadIdx.x;

    {   // one (b,k) per thread; 256 threads cover NB*K exactly; coalesced float4 rows
        const int fb = t >> 4;
        const int fk = t & 15;
        const float4* sp = (const float4*)(ss_part  + fk * NBLK + fb * BX);
        const float4* cp = (const float4*)(cnt_part + fk * NBLK + fb * BX);
        float ss = 0.0f, cc = 0.0f;
#pragma unroll
        for (int i = 0; i < BX / 4; ++i) {
            float4 v = sp[i];
            float4 w = cp[i];
            ss += v.x + v.y + v.z + v.w;
            cc += w.x + w.y + w.z + w.w;
        }
        c_sh[fb][fk] = cc;
        m_sh[fb][fk] = (cc > 0.0f) ? ss / (cc * cc) : 0.0f;
    }
    __syncthreads();

    if (t < NB) {
        int nk = 0;                               // max label value present (bins = labels 1..16)
        for (int k = K; k >= 1; --k) {
            if (c_sh[t][k - 1] > 0.0f) { nk = k; break; }
        }
        float denom = (float)(nk * (nk - 1));
        inv_denom[t] = (nk > 1) ? 1.0f / fmaxf(denom, 1.0f) : 0.0f;
    }
    __syncthreads();

    float acc = 0.0f;
    for (int e = t; e < NB * K * K; e += 256) {   // 4096 items, 16 iters
        const int fb = e >> 8;
        const int ij = e & 255;
        const int ki = ij >> 4;                   // label ki+1
        const int kj = ij & 15;                   // label kj+1
        if (kj > ki && c_sh[fb][ki] > 0.0f && c_sh[fb][kj] > 0.0f) {
            float s2 = m_sh[fb][ki] + m_sh[fb][kj];
            float dd = sqrtf(s2);
            float x  = SIGMA_DIS - dd;
            acc += log1pf(x * x) * inv_denom[fb];
        }
    }

    red[t] = acc;
    __syncthreads();
    for (int s = 128; s > 0; s >>= 1) {
        if (t < s) red[t] += red[t + s];
        __syncthreads();
    }
    if (t == 0) out[0] = red[0];
}

extern "C" void kernel_launch(void* const* d_in, const int* in_sizes, int n_in,
                              void* d_out, int out_size, void* d_ws, size_t ws_size,
                              hipStream_t stream) {
    const float* pred = (const float*)d_in[0];
    const int*   lab  = (const int*)d_in[1];
    float* out = (float*)d_out;

    float* ss_part  = (float*)d_ws;            // K*NBLK floats
    float* cnt_part = ss_part + K * NBLK;      // K*NBLK floats (256 KiB total, fully rewritten)

    dim3 grid(BX, NB);
    seg_reduce_kernel<<<grid, 256, 0, stream>>>(pred, lab, ss_part, cnt_part);
    finalize_kernel<<<1, 256, 0, stream>>>(ss_part, cnt_part, out);
}

// Round 8
// 42.595 us; speedup vs baseline: 2.5847x; 2.5847x over previous
//
#include <hip/hip_runtime.h>

#define K   16            // tracked labels 1..16 (label 0 = background, never in loss)
#define NB  16            // batch
#define NP  409600        // 640*640 pixels per image
#define NPV (NP / 4)      // 102400 float4 vectors per image
#define BX  64            // blocks per image -> 1024 blocks
#define CHUNK (NPV / BX)  // 1600 contiguous float4 per block per stream
#define NBLK (NB * BX)
#define SIGMA_DIS 3.0f

// ---------------- Stage 1: per-(b,label) sum of squared norms + counts ----------------
// Register bins (no atomics, no ballots). Contiguous chunk per block (DRAM/L2
// locality), 2-wide iterations (10 loads in flight per wave before consume).
__global__ __launch_bounds__(256) void seg_reduce_kernel(
    const float* __restrict__ pred,   // (NB, 4, NP)
    const int*   __restrict__ lab,    // (NB, NP)
    float* __restrict__ ss_part,      // (K, NBLK)  transposed for coalesced stage-2 reads
    float* __restrict__ cnt_part)     // (K, NBLK)
{
    const int tid  = threadIdx.x;
    const int lane = tid & 63;
    const int wave = tid >> 6;
    const int b    = blockIdx.y;
    const int bx   = blockIdx.x;
    const int blk  = b * BX + bx;

    float ssb[K];
    int   cnt[K];
#pragma unroll
    for (int k = 0; k < K; ++k) { ssb[k] = 0.0f; cnt[k] = 0; }

    const float4* p0 = (const float4*)(pred + ((size_t)b * 4 + 0) * NP);
    const float4* p1 = (const float4*)(pred + ((size_t)b * 4 + 1) * NP);
    const float4* p2 = (const float4*)(pred + ((size_t)b * 4 + 2) * NP);
    const float4* p3 = (const float4*)(pred + ((size_t)b * 4 + 3) * NP);
    const int4*   lb = (const int4*)(lab + (size_t)b * NP);

    const int base = bx * CHUNK;

#define ACCUM(LV, S0, S1, S2, S3)                                          \
    _Pragma("unroll")                                                      \
    for (int k = 0; k < K; ++k) {                                          \
        const int kk = k + 1;                                              \
        bool q0 = (LV.x == kk), q1 = (LV.y == kk);                         \
        bool q2 = (LV.z == kk), q3 = (LV.w == kk);                         \
        ssb[k] += (q0 ? S0 : 0.0f) + (q1 ? S1 : 0.0f)                      \
                + (q2 ? S2 : 0.0f) + (q3 ? S3 : 0.0f);                     \
        cnt[k] += (int)q0 + (int)q1 + (int)q2 + (int)q3;                   \
    }

    // 3 full 2-wide iterations cover 3*512 = 1536 of the 1600 vectors.
#pragma unroll 1
    for (int i = 0; i < 3; ++i) {
        const int v0 = base + i * 512 + tid;
        const int v1 = v0 + 256;

        // issue all 10 loads before any consume
        float4 a0 = p0[v0], c0 = p1[v0], d0 = p2[v0], e0 = p3[v0];
        float4 a1 = p0[v1], c1 = p1[v1], d1 = p2[v1], e1 = p3[v1];
        int4   l0 = lb[v0], l1 = lb[v1];

        float s00 = a0.x*a0.x + c0.x*c0.x + d0.x*d0.x + e0.x*e0.x;
        float s01 = a0.y*a0.y + c0.y*c0.y + d0.y*d0.y + e0.y*e0.y;
        float s02 = a0.z*a0.z + c0.z*c0.z + d0.z*d0.z + e0.z*e0.z;
        float s03 = a0.w*a0.w + c0.w*c0.w + d0.w*d0.w + e0.w*e0.w;
        float s10 = a1.x*a1.x + c1.x*c1.x + d1.x*d1.x + e1.x*e1.x;
        float s11 = a1.y*a1.y + c1.y*c1.y + d1.y*d1.y + e1.y*e1.y;
        float s12 = a1.z*a1.z + c1.z*c1.z + d1.z*d1.z + e1.z*e1.z;
        float s13 = a1.w*a1.w + c1.w*c1.w + d1.w*d1.w + e1.w*e1.w;

        ACCUM(l0, s00, s01, s02, s03)
        ACCUM(l1, s10, s11, s12, s13)
    }

    // tail: remaining 64 vectors of the chunk (wave 0 only)
    if (tid < CHUNK - 3 * 512) {
        const int v = base + 3 * 512 + tid;
        float4 a = p0[v], c = p1[v], d = p2[v], e = p3[v];
        int4   l = lb[v];
        float s0 = a.x*a.x + c.x*c.x + d.x*d.x + e.x*e.x;
        float s1 = a.y*a.y + c.y*c.y + d.y*d.y + e.y*e.y;
        float s2 = a.z*a.z + c.z*c.z + d.z*d.z + e.z*e.z;
        float s3 = a.w*a.w + c.w*c.w + d.w*d.w + e.w*e.w;
        ACCUM(l, s0, s1, s2, s3)
    }
#undef ACCUM

    // --- wave reduce via register butterfly (ss float, cnt int) ---
#pragma unroll
    for (int k = 0; k < K; ++k) {
#pragma unroll
        for (int m = 1; m < 64; m <<= 1) {
            ssb[k] += __shfl_xor(ssb[k], m, 64);
            cnt[k] += __shfl_xor(cnt[k], m, 64);
        }
    }

    __shared__ float ss_sh[4][K];
    __shared__ int   cnt_sh[4][K];
    if (lane == 0) {
#pragma unroll
        for (int k = 0; k < K; ++k) { ss_sh[wave][k] = ssb[k]; cnt_sh[wave][k] = cnt[k]; }
    }
    __syncthreads();

    if (tid < K) {
        float s = ss_sh[0][tid] + ss_sh[1][tid] + ss_sh[2][tid] + ss_sh[3][tid];
        float c = (float)(cnt_sh[0][tid] + cnt_sh[1][tid] + cnt_sh[2][tid] + cnt_sh[3][tid]);
        ss_part [tid * NBLK + blk] = s;
        cnt_part[tid * NBLK + blk] = c;
    }
}

// ---------------- Stage 2: combine partials + pairwise loss ----------------
__global__ __launch_bounds__(256) void finalize_kernel(
    const float* __restrict__ ss_part,
    const float* __restrict__ cnt_part,
    float* __restrict__ out)
{
    __shared__ float m_sh[NB][K];
    __shared__ float c_sh[NB][K];
    __shared__ float inv_denom[NB];
    __shared__ float red[256];

    const int t = threadIdx.x;

    {   // one (b,k) per thread; 256 threads cover NB*K exactly; coalesced float4 rows
        const int fb = t >> 4;
        const int fk = t & 15;
        const float4* sp = (const float4*)(ss_part  + fk * NBLK + fb * BX);
        const float4* cp = (const float4*)(cnt_part + fk * NBLK + fb * BX);
        float ss = 0.0f, cc = 0.0f;
#pragma unroll
        for (int i = 0; i < BX / 4; ++i) {
            float4 v = sp[i];
            float4 w = cp[i];
            ss += v.x + v.y + v.z + v.w;
            cc += w.x + w.y + w.z + w.w;
        }
        c_sh[fb][fk] = cc;
        m_sh[fb][fk] = (cc > 0.0f) ? ss / (cc * cc) : 0.0f;
    }
    __syncthreads();

    if (t < NB) {
        int nk = 0;                               // max label value present (bins = labels 1..16)
        for (int k = K; k >= 1; --k) {
            if (c_sh[t][k - 1] > 0.0f) { nk = k; break; }
        }
        float denom = (float)(nk * (nk - 1));
        inv_denom[t] = (nk > 1) ? 1.0f / fmaxf(denom, 1.0f) : 0.0f;
    }
    __syncthreads();

    float acc = 0.0f;
    for (int e = t; e < NB * K * K; e += 256) {   // 4096 items, 16 iters
        const int fb = e >> 8;
        const int ij = e & 255;
        const int ki = ij >> 4;                   // label ki+1
        const int kj = ij & 15;                   // label kj+1
        if (kj > ki && c_sh[fb][ki] > 0.0f && c_sh[fb][kj] > 0.0f) {
            float s2 = m_sh[fb][ki] + m_sh[fb][kj];
            float dd = sqrtf(s2);
            float x  = SIGMA_DIS - dd;
            acc += log1pf(x * x) * inv_denom[fb];
        }
    }

    red[t] = acc;
    __syncthreads();
    for (int s = 128; s > 0; s >>= 1) {
        if (t < s) red[t] += red[t + s];
        __syncthreads();
    }
    if (t == 0) out[0] = red[0];
}

extern "C" void kernel_launch(void* const* d_in, const int* in_sizes, int n_in,
                              void* d_out, int out_size, void* d_ws, size_t ws_size,
                              hipStream_t stream) {
    const float* pred = (const float*)d_in[0];
    const int*   lab  = (const int*)d_in[1];
    float* out = (float*)d_out;

    float* ss_part  = (float*)d_ws;            // K*NBLK floats
    float* cnt_part = ss_part + K * NBLK;      // K*NBLK floats (128 KiB total, fully rewritten)

    dim3 grid(BX, NB);
    seg_reduce_kernel<<<grid, 256, 0, stream>>>(pred, lab, ss_part, cnt_part);
    finalize_kernel<<<1, 256, 0, stream>>>(ss_part, cnt_part, out);
}